// Round 6
// baseline (49.245 us; speedup 1.0000x reference)
//
#include <hip/hip_runtime.h>
#include <hip/hip_bf16.h>
#include <stdint.h>

// Problem constants (fixed by the reference).
#define M_DIM 8192
#define K_DIM 2048
#define N_DIM 2048

typedef __attribute__((ext_vector_type(8))) short bf16x8;
typedef __attribute__((ext_vector_type(4))) float f32x4;

// fp32 -> bf16 round-to-nearest-even (data has no NaNs).
__device__ __forceinline__ ushort f2bf(float f) {
    union { float f; uint32_t u; } v; v.f = f;
    uint32_t u = v.u;
    uint32_t r = u + 0x7fffu + ((u >> 16) & 1u);
    return (ushort)(r >> 16);
}

typedef const __attribute__((address_space(1))) uint32_t gu32;
typedef __attribute__((address_space(3))) uint32_t lu32;
__device__ __forceinline__ void load_lds16(const void* g, void* l) {
    // 16B per lane, dest = wave-uniform LDS base + lane*16 (HW rule).
    __builtin_amdgcn_global_load_lds((gu32*)g, (lu32*)l, 16, 0, 0);
}

// Workspace images are byte-for-byte LDS images (XOR-swizzled), so gemm can
// stage them with linear global_load_lds and read fragments conflict-free.
//   A image: per (rb,kt) nonzero tile, 8KB: byte(r,k2) = r*128 + (k2 ^ ((r&7)<<4))
//   B image: per kt, 256KB: byte(n,k2) = n*128 + (k2 ^ ((n&7)<<4))
//
// Fused prep kernel:
//   blocks [0, 512):    two-pass scan of A: pass1 barrier-free nz-detect (full MLP),
//                       ONE barrier, pass2 re-pack nonzero tiles from L2/L3.
//   blocks [512, 1536): B (fp32 [K][N]) -> Btk swizzled k-tile-major bf16 image
__global__ __launch_bounds__(256) void prep(const float* __restrict__ A,
                                            const float* __restrict__ B,
                                            char* __restrict__ Btk,
                                            char* __restrict__ Abf,
                                            uint8_t* __restrict__ maskb) {
    __shared__ __align__(16) ushort lds[64][70];   // conv transpose buffer / scan reduce
    const int b = blockIdx.x;
    const int t = threadIdx.x;

    if (b < 512) {
        // ---- pass 1: stream 8 tiles, no barriers, per-thread 8-bit nz mask ----
        const int rb = b >> 2;
        const int seg = b & 3;
        const int r  = t >> 2;            // row in tile 0..63
        const int cs = (t & 3) << 2;      // float col base {0,4,8,12}
        const float* base = A + (size_t)(rb * 64 + r) * K_DIM + seg * 512 + cs;
        int bits = 0;
#pragma unroll
        for (int it = 0; it < 8; ++it) {
            bool nz = false;
#pragma unroll
            for (int i = 0; i < 4; ++i) {
                float4 v = *(const float4*)(base + it * 64 + i * 16);
                nz = nz || (v.x != 0.f) || (v.y != 0.f) || (v.z != 0.f) || (v.w != 0.f);
            }
            bits |= (nz ? 1 : 0) << it;
        }
        // wave OR-butterfly, then single-barrier cross-wave combine
#pragma unroll
        for (int off = 1; off < 64; off <<= 1) bits |= __shfl_xor(bits, off);
        volatile uint32_t* red = (volatile uint32_t*)&lds[0][0];
        if ((t & 63) == 0) red[t >> 6] = (uint32_t)bits;
        __syncthreads();
        const uint32_t tmask = red[0] | red[1] | red[2] | red[3];

        // ---- pass 2: re-read nonzero tiles (L2/L3-hot) and pack swizzled ----
        const int sw = (r & 7) << 4;
        uint32_t mm = tmask;
        while (mm) {
            const int it = __ffs((int)mm) - 1;
            mm &= (mm - 1);
            char* dst = Abf + (size_t)(rb * 32 + seg * 8 + it) * 8192 + r * 128;
#pragma unroll
            for (int i = 0; i < 4; ++i) {
                float4 v = *(const float4*)(base + it * 64 + i * 16);
                uint32_t lo = (uint32_t)f2bf(v.x) | ((uint32_t)f2bf(v.y) << 16);
                uint32_t hi = (uint32_t)f2bf(v.z) | ((uint32_t)f2bf(v.w) << 16);
                *(uint2*)(dst + ((cs * 2 + i * 32) ^ sw)) = make_uint2(lo, hi);
            }
        }
        if (t == 0) maskb[rb * 4 + seg] = (uint8_t)tmask;
    } else {
        // ---- conv: one 64x64 tile of B -> swizzled k-tile-major image ----
        const int c = b - 512;
        const int c0 = (c & 31) * 64;     // N offset
        const int r0 = (c >> 5) * 64;     // K offset
        const int kt = r0 >> 6;
        const int r  = t >> 2;
        const int cs = (t & 3) << 2;
#pragma unroll
        for (int i = 0; i < 4; ++i) {
            int cc = cs + i * 16;
            float4 v = *(const float4*)(B + (size_t)(r0 + r) * N_DIM + c0 + cc);
            lds[r][cc + 0] = f2bf(v.x);
            lds[r][cc + 1] = f2bf(v.y);
            lds[r][cc + 2] = f2bf(v.z);
            lds[r][cc + 3] = f2bf(v.w);
        }
        __syncthreads();
        const int ct = t >> 2;            // n within tile, 0..63
        const int s  = (t & 3) * 16;      // k segment base
        uint4 tmpv[2];
        ushort* tmp = (ushort*)tmpv;
#pragma unroll
        for (int j = 0; j < 16; ++j) tmp[j] = lds[s + j][ct];
        const int n = c0 + ct;
        char* dst = Btk + (size_t)kt * 262144 + (size_t)n * 128;
        const int swn = (n & 7) << 4;
        *(uint4*)(dst + ((s * 2)      ^ swn)) = tmpv[0];
        *(uint4*)(dst + ((s * 2 + 16) ^ swn)) = tmpv[1];
    }
}

// Block-sparse GEMM: 64x128 C tile per block, 4 waves (2Mx2N), 16x16x32 bf16 MFMA.
// Both operands staged by LINEAR global_load_lds from pre-swizzled images; k-loop
// has zero cvt / ds_write VALU. XCD-chunked cb mapping keeps each XCD's 1MB of
// Btk panels L2-resident.
__global__ __launch_bounds__(256) void gemm_sparse(const char* __restrict__ Abf,
                                                   const char* __restrict__ Btk,
                                                   const uint32_t* __restrict__ mask,
                                                   float* __restrict__ C) {
    __shared__ __align__(16) char smem[24576];         // A 8KB | B 16KB ; reused by epilogue
    char* sA = smem;                                    // [row 64][k 64] bf16, swizzled
    char* sB = smem + 8192;                             // [n 128][k 64]  bf16, swizzled

    const int orig = blockIdx.x;
    const int xcd = orig & 7;                 // assumes round-robin wg->XCD; perf-only
    const int i0 = orig >> 3;                 // 0..255
    const int cb = xcd * 2 + (i0 & 1);        // 0..15: fixed pair of cbs per XCD
    const int rb = i0 >> 1;                   // 0..127
    const int tid = threadIdx.x;
    const int lane = tid & 63;
    const int wid = tid >> 6;
    const int wm = wid >> 1;      // 0..1
    const int wn = wid & 1;       // 0..1

    f32x4 acc[2][4];
#pragma unroll
    for (int i = 0; i < 2; ++i)
#pragma unroll
        for (int j = 0; j < 4; ++j) acc[i][j] = (f32x4){0.f, 0.f, 0.f, 0.f};

    uint32_t m = mask[rb];

    while (m) {
        const int kt = __ffs((int)m) - 1;
        m &= (m - 1);

        // ---- stage B tile: 16KB, 4 linear global_load_lds per thread ----
        {
            const char* bt = Btk + (size_t)kt * 262144 + (size_t)cb * 16384;
#pragma unroll
            for (int i = 0; i < 4; ++i) {
                const int chunk = wid * 4 + i;              // 0..15, 1KB each
                load_lds16(bt + chunk * 1024 + lane * 16, sB + chunk * 1024);
            }
        }
        // ---- stage A tile: 8KB, 2 linear global_load_lds per thread ----
        {
            const char* at = Abf + (size_t)(rb * 32 + kt) * 8192;
#pragma unroll
            for (int i = 0; i < 2; ++i) {
                const int chunk = wid * 2 + i;              // 0..7, 1KB each
                load_lds16(at + chunk * 1024 + lane * 16, sA + chunk * 1024);
            }
        }
        __syncthreads();

#pragma unroll
        for (int ks = 0; ks < 2; ++ks) {
            bf16x8 af[2], bfr[4];
#pragma unroll
            for (int mf = 0; mf < 2; ++mf) {
                int row = wm * 32 + mf * 16 + (lane & 15);
                int byte = row * 128 + (ks * 32 + (lane >> 4) * 8) * 2;
                byte ^= ((row & 7) << 4);
                af[mf] = *(const bf16x8*)(sA + byte);
            }
#pragma unroll
            for (int nf = 0; nf < 4; ++nf) {
                int row = wn * 64 + nf * 16 + (lane & 15);
                int byte = row * 128 + (ks * 32 + (lane >> 4) * 8) * 2;
                byte ^= ((row & 7) << 4);
                bfr[nf] = *(const bf16x8*)(sB + byte);
            }
#pragma unroll
            for (int mf = 0; mf < 2; ++mf)
#pragma unroll
                for (int nf = 0; nf < 4; ++nf)
                    acc[mf][nf] = __builtin_amdgcn_mfma_f32_16x16x32_bf16(
                        af[mf], bfr[nf], acc[mf][nf], 0, 0, 0);
        }
        __syncthreads();
    }

    // ---- epilogue: per-wave LDS transpose -> f32x4 nontemporal stores ----
    // MFMA C/D layout: col=lane&15, row=(lane>>4)*4+reg. Each wave owns a
    // 16x66-float region (4224B); per-wave regions, no extra barrier needed.
    float* ep = (float*)(smem + wid * 4224);
    const int crow_base = rb * 64 + wm * 32;
    const int ccol_base = cb * 128 + wn * 64;
#pragma unroll
    for (int mf = 0; mf < 2; ++mf) {
#pragma unroll
        for (int nf = 0; nf < 4; ++nf)
#pragma unroll
            for (int j = 0; j < 4; ++j)
                ep[((lane >> 4) * 4 + j) * 66 + nf * 16 + (lane & 15)] = acc[mf][nf][j];
#pragma unroll
        for (int rep = 0; rep < 4; ++rep) {
            int row16 = rep * 4 + (lane >> 4);
            f32x4 v = *(const f32x4*)(ep + row16 * 66 + (lane & 15) * 4);
            float* dst = C + (size_t)(crow_base + mf * 16 + row16) * N_DIM
                         + ccol_base + (lane & 15) * 4;
            __builtin_nontemporal_store(v, (f32x4*)dst);
        }
    }
}

extern "C" void kernel_launch(void* const* d_in, const int* in_sizes, int n_in,
                              void* d_out, int out_size, void* d_ws, size_t ws_size,
                              hipStream_t stream) {
    const float* A = (const float*)d_in[0];
    const float* B = (const float*)d_in[1];
    float* C = (float*)d_out;

    // Workspace: [0,8MB) Btk image; [8MB,40MB) Abf images (128*32 tiles * 8KB);
    //            [40MB,+512) mask (128 x 4 bytes)
    char* Btk = (char*)d_ws;
    char* Abf = (char*)d_ws + (size_t)8 * 1024 * 1024;
    uint8_t* maskb = (uint8_t*)((char*)d_ws + (size_t)40 * 1024 * 1024);

    prep<<<1536, 256, 0, stream>>>(A, B, Btk, Abf, maskb);
    gemm_sparse<<<(M_DIM / 64) * (N_DIM / 128), 256, 0, stream>>>(
        Abf, Btk, (const uint32_t*)maskb, C);
}

// Round 7
// 43.374 us; speedup vs baseline: 1.1354x; 1.1354x over previous
//
#include <hip/hip_runtime.h>
#include <hip/hip_bf16.h>
#include <stdint.h>

// Problem constants (fixed by the reference).
#define M_DIM 8192
#define K_DIM 2048
#define N_DIM 2048

typedef __attribute__((ext_vector_type(8))) short bf16x8;
typedef __attribute__((ext_vector_type(4))) float f32x4;

// fp32 -> bf16 round-to-nearest-even (data has no NaNs).
__device__ __forceinline__ ushort f2bf(float f) {
    union { float f; uint32_t u; } v; v.f = f;
    uint32_t u = v.u;
    uint32_t r = u + 0x7fffu + ((u >> 16) & 1u);
    return (ushort)(r >> 16);
}

typedef const __attribute__((address_space(1))) uint32_t gu32;
typedef __attribute__((address_space(3))) uint32_t lu32;
__device__ __forceinline__ void load_lds16(const void* g, void* l) {
    // 16B per lane, dest = wave-uniform LDS base + lane*16 (HW rule).
    __builtin_amdgcn_global_load_lds((gu32*)g, (lu32*)l, 16, 0, 0);
}

// Workspace images are byte-for-byte LDS images (XOR-swizzled), so gemm can
// stage them with linear global_load_lds and read fragments conflict-free.
//   A image: per tile (rb*32+kt), 8KB: byte(r,k2) = r*128 + (k2 ^ ((r&7)<<4))
//   B image: per kt, 256KB: byte(n,k2) = n*128 + (k2 ^ ((n&7)<<4))
//
// Fused prep kernel:
//   blocks [0, 1024):    barrier-free wave-per-tile scan of A. Each wave: 16
//                        256B-coalesced loads/lane, __any nz, pack from regs.
//                        Mask is a byte per tile (no atomics, no pre-zero).
//   blocks [1024, 2048): B (fp32 [K][N]) -> Btk swizzled k-tile-major bf16 image
__global__ __launch_bounds__(256) void prep(const float* __restrict__ A,
                                            const float* __restrict__ B,
                                            char* __restrict__ Btk,
                                            char* __restrict__ Abf,
                                            uint8_t* __restrict__ maskb) {
    __shared__ __align__(16) ushort lds[64][70];   // conv transpose buffer only
    const int b = blockIdx.x;
    const int t = threadIdx.x;

    if (b < 1024) {
        // ---- scan: one 64x64 tile per wave, no barriers ----
        const int wid = t >> 6;
        const int lane = t & 63;
        const int tile = b * 4 + wid;            // 0..4095
        const int rb = tile >> 5;                // 0..127
        const int kt = tile & 31;                // 0..31
        const int r0 = lane >> 4;                // 0..3
        const int c4 = (lane & 15) << 2;         // float col 0..60
        const float* base = A + (size_t)(rb * 64) * K_DIM + kt * 64 + c4;
        float4 v[16];
        bool nz = false;
#pragma unroll
        for (int i = 0; i < 16; ++i) {
            const int row = r0 + i * 4;
            v[i] = *(const float4*)(base + (size_t)row * K_DIM);
            nz = nz || (v[i].x != 0.f) || (v[i].y != 0.f) ||
                       (v[i].z != 0.f) || (v[i].w != 0.f);
        }
        const bool tnz = __any((int)nz);
        if (tnz) {
            char* dst = Abf + (size_t)tile * 8192;
#pragma unroll
            for (int i = 0; i < 16; ++i) {
                const int row = r0 + i * 4;
                uint32_t lo = (uint32_t)f2bf(v[i].x) | ((uint32_t)f2bf(v[i].y) << 16);
                uint32_t hi = (uint32_t)f2bf(v[i].z) | ((uint32_t)f2bf(v[i].w) << 16);
                *(uint2*)(dst + row * 128 + ((c4 * 2) ^ ((row & 7) << 4))) =
                    make_uint2(lo, hi);
            }
        }
        if (lane == 0) maskb[tile] = tnz ? 1 : 0;
    } else {
        // ---- conv: one 64x64 tile of B -> swizzled k-tile-major image ----
        const int c = b - 1024;
        const int c0 = (c & 31) * 64;     // N offset
        const int r0 = (c >> 5) * 64;     // K offset
        const int kt = r0 >> 6;
        const int r  = t >> 2;
        const int cs = (t & 3) << 2;
#pragma unroll
        for (int i = 0; i < 4; ++i) {
            int cc = cs + i * 16;
            float4 v = *(const float4*)(B + (size_t)(r0 + r) * N_DIM + c0 + cc);
            lds[r][cc + 0] = f2bf(v.x);
            lds[r][cc + 1] = f2bf(v.y);
            lds[r][cc + 2] = f2bf(v.z);
            lds[r][cc + 3] = f2bf(v.w);
        }
        __syncthreads();
        const int ct = t >> 2;            // n within tile, 0..63
        const int s  = (t & 3) * 16;      // k segment base
        uint4 tmpv[2];
        ushort* tmp = (ushort*)tmpv;
#pragma unroll
        for (int j = 0; j < 16; ++j) tmp[j] = lds[s + j][ct];
        const int n = c0 + ct;
        char* dst = Btk + (size_t)kt * 262144 + (size_t)n * 128;
        const int swn = (n & 7) << 4;
        *(uint4*)(dst + ((s * 2)      ^ swn)) = tmpv[0];
        *(uint4*)(dst + ((s * 2 + 16) ^ swn)) = tmpv[1];
    }
}

// Block-sparse GEMM: 64x128 C tile per block, 4 waves (2Mx2N), 16x16x32 bf16 MFMA.
// Both operands staged by LINEAR global_load_lds from pre-swizzled images; k-loop
// has zero cvt / ds_write VALU. XCD-chunked cb mapping keeps each XCD's 1MB of
// Btk panels L2-resident.
__global__ __launch_bounds__(256) void gemm_sparse(const char* __restrict__ Abf,
                                                   const char* __restrict__ Btk,
                                                   const uint8_t* __restrict__ maskb,
                                                   float* __restrict__ C) {
    __shared__ __align__(16) char smem[24576];         // A 8KB | B 16KB ; reused by epilogue
    char* sA = smem;                                    // [row 64][k 64] bf16, swizzled
    char* sB = smem + 8192;                             // [n 128][k 64]  bf16, swizzled

    const int orig = blockIdx.x;
    const int xcd = orig & 7;                 // assumes round-robin wg->XCD; perf-only
    const int i0 = orig >> 3;                 // 0..255
    const int cb = xcd * 2 + (i0 & 1);        // 0..15: fixed pair of cbs per XCD
    const int rb = i0 >> 1;                   // 0..127
    const int tid = threadIdx.x;
    const int lane = tid & 63;
    const int wid = tid >> 6;
    const int wm = wid >> 1;      // 0..1
    const int wn = wid & 1;       // 0..1

    f32x4 acc[2][4];
#pragma unroll
    for (int i = 0; i < 2; ++i)
#pragma unroll
        for (int j = 0; j < 4; ++j) acc[i][j] = (f32x4){0.f, 0.f, 0.f, 0.f};

    // build the k-tile bitmask from 32 mask bytes (uniform across block)
    const uint8_t* mb = maskb + rb * 32;
    uint32_t m = 0;
#pragma unroll
    for (int i = 0; i < 32; ++i) m |= (mb[i] ? 1u : 0u) << i;

    while (m) {
        const int kt = __ffs((int)m) - 1;
        m &= (m - 1);

        // ---- stage B tile: 16KB, 4 linear global_load_lds per thread ----
        {
            const char* bt = Btk + (size_t)kt * 262144 + (size_t)cb * 16384;
#pragma unroll
            for (int i = 0; i < 4; ++i) {
                const int chunk = wid * 4 + i;              // 0..15, 1KB each
                load_lds16(bt + chunk * 1024 + lane * 16, sB + chunk * 1024);
            }
        }
        // ---- stage A tile: 8KB, 2 linear global_load_lds per thread ----
        {
            const char* at = Abf + (size_t)(rb * 32 + kt) * 8192;
#pragma unroll
            for (int i = 0; i < 2; ++i) {
                const int chunk = wid * 2 + i;              // 0..7, 1KB each
                load_lds16(at + chunk * 1024 + lane * 16, sA + chunk * 1024);
            }
        }
        __syncthreads();

#pragma unroll
        for (int ks = 0; ks < 2; ++ks) {
            bf16x8 af[2], bfr[4];
#pragma unroll
            for (int mf = 0; mf < 2; ++mf) {
                int row = wm * 32 + mf * 16 + (lane & 15);
                int byte = row * 128 + (ks * 32 + (lane >> 4) * 8) * 2;
                byte ^= ((row & 7) << 4);
                af[mf] = *(const bf16x8*)(sA + byte);
            }
#pragma unroll
            for (int nf = 0; nf < 4; ++nf) {
                int row = wn * 64 + nf * 16 + (lane & 15);
                int byte = row * 128 + (ks * 32 + (lane >> 4) * 8) * 2;
                byte ^= ((row & 7) << 4);
                bfr[nf] = *(const bf16x8*)(sB + byte);
            }
#pragma unroll
            for (int mf = 0; mf < 2; ++mf)
#pragma unroll
                for (int nf = 0; nf < 4; ++nf)
                    acc[mf][nf] = __builtin_amdgcn_mfma_f32_16x16x32_bf16(
                        af[mf], bfr[nf], acc[mf][nf], 0, 0, 0);
        }
        __syncthreads();
    }

    // ---- epilogue: per-wave LDS transpose -> f32x4 nontemporal stores ----
    // MFMA C/D layout: col=lane&15, row=(lane>>4)*4+reg. Each wave owns a
    // 16x66-float region (4224B); per-wave regions, no extra barrier needed.
    float* ep = (float*)(smem + wid * 4224);
    const int crow_base = rb * 64 + wm * 32;
    const int ccol_base = cb * 128 + wn * 64;
#pragma unroll
    for (int mf = 0; mf < 2; ++mf) {
#pragma unroll
        for (int nf = 0; nf < 4; ++nf)
#pragma unroll
            for (int j = 0; j < 4; ++j)
                ep[((lane >> 4) * 4 + j) * 66 + nf * 16 + (lane & 15)] = acc[mf][nf][j];
#pragma unroll
        for (int rep = 0; rep < 4; ++rep) {
            int row16 = rep * 4 + (lane >> 4);
            f32x4 v = *(const f32x4*)(ep + row16 * 66 + (lane & 15) * 4);
            float* dst = C + (size_t)(crow_base + mf * 16 + row16) * N_DIM
                         + ccol_base + (lane & 15) * 4;
            __builtin_nontemporal_store(v, (f32x4*)dst);
        }
    }
}

extern "C" void kernel_launch(void* const* d_in, const int* in_sizes, int n_in,
                              void* d_out, int out_size, void* d_ws, size_t ws_size,
                              hipStream_t stream) {
    const float* A = (const float*)d_in[0];
    const float* B = (const float*)d_in[1];
    float* C = (float*)d_out;

    // Workspace: [0,8MB) Btk image; [8MB,40MB) Abf images (4096 tiles * 8KB);
    //            [40MB,+4KB) mask (4096 bytes, one per tile)
    char* Btk = (char*)d_ws;
    char* Abf = (char*)d_ws + (size_t)8 * 1024 * 1024;
    uint8_t* maskb = (uint8_t*)((char*)d_ws + (size_t)40 * 1024 * 1024);

    prep<<<2048, 256, 0, stream>>>(A, B, Btk, Abf, maskb);
    gemm_sparse<<<(M_DIM / 64) * (N_DIM / 128), 256, 0, stream>>>(
        Abf, Btk, maskb, C);
}

// Round 9
// 40.960 us; speedup vs baseline: 1.2023x; 1.0589x over previous
//
#include <hip/hip_runtime.h>
#include <hip/hip_bf16.h>
#include <stdint.h>

// Problem constants (fixed by the reference).
#define M_DIM 8192
#define K_DIM 2048
#define N_DIM 2048

typedef __attribute__((ext_vector_type(8))) short bf16x8;
typedef __attribute__((ext_vector_type(4))) float f32x4;

// fp32 -> bf16 round-to-nearest-even (data has no NaNs).
__device__ __forceinline__ ushort f2bf(float f) {
    union { float f; uint32_t u; } v; v.f = f;
    uint32_t u = v.u;
    uint32_t r = u + 0x7fffu + ((u >> 16) & 1u);
    return (ushort)(r >> 16);
}

typedef const __attribute__((address_space(1))) uint32_t gu32;
typedef __attribute__((address_space(3))) uint32_t lu32;
__device__ __forceinline__ void load_lds16(const void* g, void* l) {
    // 16B per lane, dest = wave-uniform LDS base + lane*16 (HW rule).
    __builtin_amdgcn_global_load_lds((gu32*)g, (lu32*)l, 16, 0, 0);
}

// Workspace images are byte-for-byte LDS images (XOR-swizzled), so gemm can
// stage them with linear global_load_lds and read fragments conflict-free.
//   A image: per tile (rb*32+kt), 8KB: byte(r,k2) = r*128 + (k2 ^ ((r&7)<<4))
//   B image: per kt, 256KB: byte(n,k2) = n*128 + (k2 ^ ((n&7)<<4))
//
// Fused prep kernel (byte-identical to the round-5 version, best measured):
//   blocks [0, 512):    scan A (pipelined loads) -> byte mask + packed bf16 A tiles
//   blocks [512, 1536): B (fp32 [K][N]) -> Btk swizzled k-tile-major bf16 image
__global__ __launch_bounds__(256) void prep(const float* __restrict__ A,
                                            const float* __restrict__ B,
                                            char* __restrict__ Btk,
                                            char* __restrict__ Abf,
                                            uint8_t* __restrict__ maskb) {
    __shared__ __align__(16) ushort lds[64][70];
    const int b = blockIdx.x;
    const int t = threadIdx.x;

    if (b < 512) {
        // ---- scan + pack: 8 k-tiles of one row-block quarter ----
        const int rb = b >> 2;
        const int seg = b & 3;
        const int r  = t >> 2;            // row in tile 0..63
        const int cs = (t & 3) << 2;      // float col base {0,4,8,12}; +i*16
        const float* base = A + (size_t)(rb * 64 + r) * K_DIM + seg * 512 + cs;
        const int sw = (r & 7) << 4;
        uint32_t outb = 0;
        float4 cur[4], nxt[4];
#pragma unroll
        for (int i = 0; i < 4; ++i) cur[i] = *(const float4*)(base + i * 16);
#pragma unroll
        for (int it = 0; it < 8; ++it) {
            if (it < 7) {
#pragma unroll
                for (int i = 0; i < 4; ++i) nxt[i] = *(const float4*)(base + (it + 1) * 64 + i * 16);
            }
            bool nz = false;
#pragma unroll
            for (int i = 0; i < 4; ++i)
                nz = nz || (cur[i].x != 0.f) || (cur[i].y != 0.f) ||
                           (cur[i].z != 0.f) || (cur[i].w != 0.f);
            int anynz = __syncthreads_or((int)nz);
            if (anynz) {
                outb |= 1u << it;
                char* dst = Abf + (size_t)(rb * 32 + seg * 8 + it) * 8192 + r * 128;
#pragma unroll
                for (int i = 0; i < 4; ++i) {
                    uint32_t lo = (uint32_t)f2bf(cur[i].x) | ((uint32_t)f2bf(cur[i].y) << 16);
                    uint32_t hi = (uint32_t)f2bf(cur[i].z) | ((uint32_t)f2bf(cur[i].w) << 16);
                    *(uint2*)(dst + ((cs * 2 + i * 32) ^ sw)) = make_uint2(lo, hi);
                }
            }
#pragma unroll
            for (int i = 0; i < 4; ++i) cur[i] = nxt[i];
        }
        if (t == 0) maskb[rb * 4 + seg] = (uint8_t)outb;
    } else {
        // ---- conv: one 64x64 tile of B -> swizzled k-tile-major image ----
        const int c = b - 512;
        const int c0 = (c & 31) * 64;     // N offset
        const int r0 = (c >> 5) * 64;     // K offset
        const int kt = r0 >> 6;
        const int r  = t >> 2;
        const int cs = (t & 3) << 2;
#pragma unroll
        for (int i = 0; i < 4; ++i) {
            int cc = cs + i * 16;
            float4 v = *(const float4*)(B + (size_t)(r0 + r) * N_DIM + c0 + cc);
            lds[r][cc + 0] = f2bf(v.x);
            lds[r][cc + 1] = f2bf(v.y);
            lds[r][cc + 2] = f2bf(v.z);
            lds[r][cc + 3] = f2bf(v.w);
        }
        __syncthreads();
        const int ct = t >> 2;            // n within tile, 0..63
        const int s  = (t & 3) * 16;      // k segment base
        uint4 tmpv[2];
        ushort* tmp = (ushort*)tmpv;
#pragma unroll
        for (int j = 0; j < 16; ++j) tmp[j] = lds[s + j][ct];
        const int n = c0 + ct;
        char* dst = Btk + (size_t)kt * 262144 + (size_t)n * 128;
        const int swn = (n & 7) << 4;
        *(uint4*)(dst + ((s * 2)      ^ swn)) = tmpv[0];
        *(uint4*)(dst + ((s * 2 + 16) ^ swn)) = tmpv[1];
    }
}

// Block-sparse GEMM: 64x128 C tile per block, 4 waves (2Mx2N), 16x16x32 bf16 MFMA.
// Double-buffered staging (T3/T4-lite): next k-tile's global_load_lds issued
// BEFORE the current MFMA phase; counted s_waitcnt vmcnt(6) (never a vmcnt(0)
// drain in steady state) so prefetch loads stay in flight across the barrier.
__global__ __launch_bounds__(256) void gemm_sparse(const char* __restrict__ Abf,
                                                   const char* __restrict__ Btk,
                                                   const uint32_t* __restrict__ mask,
                                                   float* __restrict__ C) {
    // layout: [A0 8K][A1 8K][B0 16K][B1 16K] = 48KB; epilogue reuses [0,16.9K)
    __shared__ __align__(16) char smem[49152];

    const int orig = blockIdx.x;
    const int xcd = orig & 7;                 // assumes round-robin wg->XCD; perf-only
    const int i0 = orig >> 3;                 // 0..255
    const int cb = xcd * 2 + (i0 & 1);        // 0..15: fixed pair of cbs per XCD
    const int rb = i0 >> 1;                   // 0..127
    const int tid = threadIdx.x;
    const int lane = tid & 63;
    const int wid = tid >> 6;
    const int wm = wid >> 1;      // 0..1
    const int wn = wid & 1;       // 0..1

    f32x4 acc[2][4];
#pragma unroll
    for (int i = 0; i < 2; ++i)
#pragma unroll
        for (int j = 0; j < 4; ++j) acc[i][j] = (f32x4){0.f, 0.f, 0.f, 0.f};

    uint32_t m = mask[rb];

    // 6 vector loads per thread per tile (4 B-chunks + 2 A-chunks).
#define STAGE_TILE(PBUF, KT)                                                     \
    do {                                                                         \
        const char* bt_ = Btk + (size_t)(KT) * 262144 + (size_t)cb * 16384;      \
        char* sBp_ = smem + 16384 + (PBUF) * 16384;                              \
        _Pragma("unroll")                                                        \
        for (int i_ = 0; i_ < 4; ++i_) {                                         \
            const int ch_ = wid * 4 + i_;                                        \
            load_lds16(bt_ + ch_ * 1024 + lane * 16, sBp_ + ch_ * 1024);         \
        }                                                                        \
        const char* at_ = Abf + (size_t)(rb * 32 + (KT)) * 8192;                 \
        char* sAp_ = smem + (PBUF) * 8192;                                       \
        _Pragma("unroll")                                                        \
        for (int i_ = 0; i_ < 2; ++i_) {                                         \
            const int ch_ = wid * 2 + i_;                                        \
            load_lds16(at_ + ch_ * 1024 + lane * 16, sAp_ + ch_ * 1024);         \
        }                                                                        \
    } while (0)

    if (m) {
        int kt = __ffs((int)m) - 1;
        m &= (m - 1);
        STAGE_TILE(0, kt);
        int p = 0;
        for (;;) {
            int ktn = -1;
            if (m) {
                ktn = __ffs((int)m) - 1;
                m &= (m - 1);
                STAGE_TILE(p ^ 1, ktn);          // prefetch next tile (other buffer)
                asm volatile("s_waitcnt vmcnt(6)" ::: "memory");  // cur's 6 retired
            } else {
                asm volatile("s_waitcnt vmcnt(0)" ::: "memory");  // last tile: drain
            }
            __builtin_amdgcn_s_barrier();          // all threads' cur data in LDS
            __builtin_amdgcn_sched_barrier(0);     // pin ds_reads below barrier

            const char* sAp = smem + p * 8192;
            const char* sBp = smem + 16384 + p * 16384;
#pragma unroll
            for (int ks = 0; ks < 2; ++ks) {
                bf16x8 af[2], bfr[4];
#pragma unroll
                for (int mf = 0; mf < 2; ++mf) {
                    int row = wm * 32 + mf * 16 + (lane & 15);
                    int byte = row * 128 + (ks * 32 + (lane >> 4) * 8) * 2;
                    byte ^= ((row & 7) << 4);
                    af[mf] = *(const bf16x8*)(sAp + byte);
                }
#pragma unroll
                for (int nf = 0; nf < 4; ++nf) {
                    int row = wn * 64 + nf * 16 + (lane & 15);
                    int byte = row * 128 + (ks * 32 + (lane >> 4) * 8) * 2;
                    byte ^= ((row & 7) << 4);
                    bfr[nf] = *(const bf16x8*)(sBp + byte);
                }
#pragma unroll
                for (int mf = 0; mf < 2; ++mf)
#pragma unroll
                    for (int nf = 0; nf < 4; ++nf)
                        acc[mf][nf] = __builtin_amdgcn_mfma_f32_16x16x32_bf16(
                            af[mf], bfr[nf], acc[mf][nf], 0, 0, 0);
            }
            if (ktn < 0) break;
            __builtin_amdgcn_sched_barrier(0);
            __builtin_amdgcn_s_barrier();          // buf p consumed -> reusable
            p ^= 1;
            kt = ktn;
        }
    }
#undef STAGE_TILE

    __syncthreads();   // protect smem reuse by epilogue

    // ---- epilogue: per-wave LDS transpose -> f32x4 nontemporal stores ----
    // MFMA C/D layout: col=lane&15, row=(lane>>4)*4+reg. Each wave owns a
    // 16x66-float region (4224B); per-wave regions, no further barrier needed.
    float* ep = (float*)(smem + wid * 4224);
    const int crow_base = rb * 64 + wm * 32;
    const int ccol_base = cb * 128 + wn * 64;
#pragma unroll
    for (int mf = 0; mf < 2; ++mf) {
#pragma unroll
        for (int nf = 0; nf < 4; ++nf)
#pragma unroll
            for (int j = 0; j < 4; ++j)
                ep[((lane >> 4) * 4 + j) * 66 + nf * 16 + (lane & 15)] = acc[mf][nf][j];
#pragma unroll
        for (int rep = 0; rep < 4; ++rep) {
            int row16 = rep * 4 + (lane >> 4);
            f32x4 v = *(const f32x4*)(ep + row16 * 66 + (lane & 15) * 4);
            float* dst = C + (size_t)(crow_base + mf * 16 + row16) * N_DIM
                         + ccol_base + (lane & 15) * 4;
            __builtin_nontemporal_store(v, (f32x4*)dst);
        }
    }
}

extern "C" void kernel_launch(void* const* d_in, const int* in_sizes, int n_in,
                              void* d_out, int out_size, void* d_ws, size_t ws_size,
                              hipStream_t stream) {
    const float* A = (const float*)d_in[0];
    const float* B = (const float*)d_in[1];
    float* C = (float*)d_out;

    // Workspace: [0,8MB) Btk image; [8MB,40MB) Abf images (4096 tiles * 8KB);
    //            [40MB,+512) mask (128 x 4 bytes)
    char* Btk = (char*)d_ws;
    char* Abf = (char*)d_ws + (size_t)8 * 1024 * 1024;
    uint8_t* maskb = (uint8_t*)((char*)d_ws + (size_t)40 * 1024 * 1024);

    prep<<<1536, 256, 0, stream>>>(A, B, Btk, Abf, maskb);
    gemm_sparse<<<(M_DIM / 64) * (N_DIM / 128), 256, 0, stream>>>(
        Abf, Btk, (const uint32_t*)maskb, C);
}